// Round 2
// baseline (207.013 us; speedup 1.0000x reference)
//
#include <hip/hip_runtime.h>

#define BINS 128
#define FEAT 64
#define SEG (BINS * FEAT)   // 8192 counters per (b)-histogram
#define B_DIM 32
#define S_DIM 16384
#define CHUNKS 32           // S-chunks per batch -> 1024 blocks = 4 blocks/CU
#define THREADS 512         // 8 waves
#define UNROLL 8

// ---------- Primary path: partials to workspace, no global atomics ----------

// grid = (CHUNKS, B_DIM), block = THREADS.
// Each block: LDS uint histogram over its 512-row S-chunk, then coalesced
// NON-atomic partial write to ws[b][chunk][SEG].
// launch_bounds(512,8): 8 waves/EU = 4 blocks/CU co-resident (LDS 4x32K=128K ok),
// doubling latency-hiding waves AND independent DS-pipe histograms vs round 1.
__global__ __launch_bounds__(THREADS, 8)
void hist_part(const float* __restrict__ x, unsigned* __restrict__ part) {
    __shared__ unsigned hist[SEG];
    for (int i = threadIdx.x; i < SEG; i += THREADS) hist[i] = 0u;
    __syncthreads();

    const int b    = blockIdx.y;
    const int lane = threadIdx.x & 63;
    const int wave = threadIdx.x >> 6;                 // 0..7
    const int chunk = S_DIM / CHUNKS;                  // 512 rows per block
    const int rows_per_wave = chunk / (THREADS / 64);  // 64

    const float* xb = x + (size_t)b * S_DIM * FEAT;
    const int s0 = blockIdx.x * chunk + wave * rows_per_wave;

    for (int it = 0; it < rows_per_wave; it += UNROLL) {
        float v[UNROLL];
        #pragma unroll
        for (int u = 0; u < UNROLL; ++u)
            v[u] = xb[(size_t)(s0 + it + u) * FEAT + lane];   // coalesced 256B/wave
        #pragma unroll
        for (int u = 0; u < UNROLL; ++u) {
            int bin = (int)(v[u] * 128.0f);            // exact trunc like ref
            bin = bin < 0 ? 0 : (bin > 127 ? 127 : bin);
            // addr = bin*64 + lane -> distinct addr per lane, bank = lane%32 (free 2-way)
            atomicAdd(&hist[(bin << 6) + lane], 1u);   // ds_add_u32
        }
    }
    __syncthreads();

    unsigned* p = part + ((size_t)(b * CHUNKS + blockIdx.x)) * SEG;
    for (int i = threadIdx.x; i < SEG; i += THREADS)
        __builtin_nontemporal_store(hist[i], &p[i]);   // streaming partials, skip L2
}

// out[b][i] = (sum_c part[b][c][i]) * w[i]; uint4/float4 vectorized, fully coalesced.
__global__ __launch_bounds__(256)
void reduce_fin(const unsigned* __restrict__ part, float* __restrict__ out,
                const float* __restrict__ w) {
    int t = blockIdx.x * blockDim.x + threadIdx.x;     // 0 .. B*SEG/4-1 (=65536)
    if (t >= B_DIM * (SEG / 4)) return;
    int b = t >> 11;                                   // SEG/4 = 2048 uint4 per seg
    int q = t & 2047;
    const uint4* base = (const uint4*)(part + (size_t)b * CHUNKS * SEG) + q;
    unsigned s0 = 0, s1 = 0, s2 = 0, s3 = 0;
    #pragma unroll
    for (int c = 0; c < CHUNKS; ++c) {
        uint4 v = base[(size_t)c * (SEG / 4)];
        s0 += v.x; s1 += v.y; s2 += v.z; s3 += v.w;
    }
    float4 wv = ((const float4*)w)[q];                 // weight idx = i (i < SEG)
    float4 o;
    o.x = (float)s0 * wv.x;
    o.y = (float)s1 * wv.y;
    o.z = (float)s2 * wv.z;
    o.w = (float)s3 * wv.w;
    ((float4*)out)[(size_t)b * (SEG / 4) + q] = o;     // overwrites poison
}

// ---------- Fallback path (ws too small): global-atomic version ----------

__global__ __launch_bounds__(THREADS, 2)
void hist_kernel(const float* __restrict__ x, unsigned* out) {
    __shared__ unsigned hist[SEG];
    for (int i = threadIdx.x; i < SEG; i += THREADS) hist[i] = 0u;
    __syncthreads();

    const int b    = blockIdx.y;
    const int lane = threadIdx.x & 63;
    const int wave = threadIdx.x >> 6;
    const int chunk = S_DIM / CHUNKS;
    const int rows_per_wave = chunk / (THREADS / 64);

    const float* xb = x + (size_t)b * S_DIM * FEAT;
    const int s0 = blockIdx.x * chunk + wave * rows_per_wave;

    for (int it = 0; it < rows_per_wave; it += UNROLL) {
        float v[UNROLL];
        #pragma unroll
        for (int u = 0; u < UNROLL; ++u)
            v[u] = xb[(size_t)(s0 + it + u) * FEAT + lane];
        #pragma unroll
        for (int u = 0; u < UNROLL; ++u) {
            int bin = (int)(v[u] * 128.0f);
            bin = bin < 0 ? 0 : (bin > 127 ? 127 : bin);
            atomicAdd(&hist[(bin << 6) + lane], 1u);
        }
    }
    __syncthreads();

    unsigned* gout = out + (size_t)b * SEG;
    for (int i = threadIdx.x; i < SEG; i += THREADS) {
        unsigned c = hist[i];
        if (c) atomicAdd(&gout[i], c);
    }
}

__global__ void finalize_kernel(const unsigned* cnt, float* out,
                                const float* __restrict__ w, int n) {
    int i = blockIdx.x * blockDim.x + threadIdx.x;
    if (i < n) {
        unsigned c = cnt[i];
        out[i] = (float)c * w[i & (SEG - 1)];
    }
}

extern "C" void kernel_launch(void* const* d_in, const int* in_sizes, int n_in,
                              void* d_out, int out_size, void* d_ws, size_t ws_size,
                              hipStream_t stream) {
    const float* x = (const float*)d_in[0];
    const float* w = (const float*)d_in[1];
    float* out = (float*)d_out;

    const size_t ws_needed = (size_t)B_DIM * CHUNKS * SEG * sizeof(unsigned); // 32 MiB

    if (ws_size >= ws_needed && d_ws != nullptr) {
        unsigned* part = (unsigned*)d_ws;
        dim3 grid(CHUNKS, B_DIM);
        hist_part<<<grid, THREADS, 0, stream>>>(x, part);
        int nt = B_DIM * (SEG / 4);                    // 65536 threads
        reduce_fin<<<(nt + 255) / 256, 256, 0, stream>>>(part, out, w);
    } else {
        // Fallback: old path with global atomic merge.
        hipMemsetAsync(d_out, 0, (size_t)out_size * sizeof(float), stream);
        dim3 grid(CHUNKS, B_DIM);
        hist_kernel<<<grid, THREADS, 0, stream>>>(x, (unsigned*)d_out);
        int n = out_size;
        finalize_kernel<<<(n + 255) / 256, 256, 0, stream>>>((const unsigned*)d_out, out, w, n);
    }
}

// Round 3
// 192.221 us; speedup vs baseline: 1.0770x; 1.0770x over previous
//
#include <hip/hip_runtime.h>

#define BINS 128
#define FEAT 64
#define SEG (BINS * FEAT)   // 8192 counters per (b)-histogram
#define B_DIM 32
#define S_DIM 16384
#define CHUNKS 16           // S-chunks per batch -> 512 blocks = 2 blocks/CU
#define THREADS 512         // 8 waves
#define UNROLL 8

// ---------- Primary path: partials to workspace, no global atomics ----------

// grid = (CHUNKS, B_DIM), block = THREADS.
// Each block: LDS uint histogram over its 1024-row S-chunk, then coalesced
// NON-atomic partial write to ws[b][chunk][SEG].
// Round-2 lesson: 4 blocks/CU (CHUNKS=32) + nt-stores was SLOWER (-10us):
// hist is BW-bound, not occupancy-bound, and partials must stay in L2/L3
// so reduce_fin reads them without an HBM round-trip. So: CHUNKS=16,
// plain stores for partials, nontemporal loads for the 128MiB streaming input.
__global__ __launch_bounds__(THREADS, 2)
void hist_part(const float* __restrict__ x, unsigned* __restrict__ part) {
    __shared__ unsigned hist[SEG];
    for (int i = threadIdx.x; i < SEG; i += THREADS) hist[i] = 0u;
    __syncthreads();

    const int b    = blockIdx.y;
    const int lane = threadIdx.x & 63;
    const int wave = threadIdx.x >> 6;                 // 0..7
    const int chunk = S_DIM / CHUNKS;                  // 1024 rows per block
    const int rows_per_wave = chunk / (THREADS / 64);  // 128

    const float* xb = x + (size_t)b * S_DIM * FEAT;
    const int s0 = blockIdx.x * chunk + wave * rows_per_wave;

    for (int it = 0; it < rows_per_wave; it += UNROLL) {
        float v[UNROLL];
        #pragma unroll
        for (int u = 0; u < UNROLL; ++u)
            v[u] = __builtin_nontemporal_load(
                       &xb[(size_t)(s0 + it + u) * FEAT + lane]);  // coalesced 256B/wave
        #pragma unroll
        for (int u = 0; u < UNROLL; ++u) {
            int bin = (int)(v[u] * 128.0f);            // exact trunc like ref
            bin = bin < 0 ? 0 : (bin > 127 ? 127 : bin);   // -> v_med3_i32
            // addr = bin*64 + lane -> distinct addr per lane, bank = lane%32 (free 2-way)
            atomicAdd(&hist[(bin << 6) + lane], 1u);   // ds_add_u32
        }
    }
    __syncthreads();

    unsigned* p = part + ((size_t)(b * CHUNKS + blockIdx.x)) * SEG;
    for (int i = threadIdx.x; i < SEG; i += THREADS)
        p[i] = hist[i];                                // plain store -> stays in L2/L3
}

// out[b][i] = (sum_c part[b][c][i]) * w[i]; uint4/float4 vectorized, fully coalesced.
__global__ __launch_bounds__(256)
void reduce_fin(const unsigned* __restrict__ part, float* __restrict__ out,
                const float* __restrict__ w) {
    int t = blockIdx.x * blockDim.x + threadIdx.x;     // 0 .. B*SEG/4-1 (=65536)
    if (t >= B_DIM * (SEG / 4)) return;
    int b = t >> 11;                                   // SEG/4 = 2048 uint4 per seg
    int q = t & 2047;
    const uint4* base = (const uint4*)(part + (size_t)b * CHUNKS * SEG) + q;
    unsigned s0 = 0, s1 = 0, s2 = 0, s3 = 0;
    #pragma unroll
    for (int c = 0; c < CHUNKS; ++c) {
        uint4 v = base[(size_t)c * (SEG / 4)];
        s0 += v.x; s1 += v.y; s2 += v.z; s3 += v.w;
    }
    float4 wv = ((const float4*)w)[q];                 // weight idx = i (i < SEG)
    float4 o;
    o.x = (float)s0 * wv.x;
    o.y = (float)s1 * wv.y;
    o.z = (float)s2 * wv.z;
    o.w = (float)s3 * wv.w;
    ((float4*)out)[(size_t)b * (SEG / 4) + q] = o;     // overwrites poison
}

// ---------- Fallback path (ws too small): global-atomic version ----------

__global__ __launch_bounds__(THREADS, 2)
void hist_kernel(const float* __restrict__ x, unsigned* out) {
    __shared__ unsigned hist[SEG];
    for (int i = threadIdx.x; i < SEG; i += THREADS) hist[i] = 0u;
    __syncthreads();

    const int b    = blockIdx.y;
    const int lane = threadIdx.x & 63;
    const int wave = threadIdx.x >> 6;
    const int chunk = S_DIM / CHUNKS;
    const int rows_per_wave = chunk / (THREADS / 64);

    const float* xb = x + (size_t)b * S_DIM * FEAT;
    const int s0 = blockIdx.x * chunk + wave * rows_per_wave;

    for (int it = 0; it < rows_per_wave; it += UNROLL) {
        float v[UNROLL];
        #pragma unroll
        for (int u = 0; u < UNROLL; ++u)
            v[u] = xb[(size_t)(s0 + it + u) * FEAT + lane];
        #pragma unroll
        for (int u = 0; u < UNROLL; ++u) {
            int bin = (int)(v[u] * 128.0f);
            bin = bin < 0 ? 0 : (bin > 127 ? 127 : bin);
            atomicAdd(&hist[(bin << 6) + lane], 1u);
        }
    }
    __syncthreads();

    unsigned* gout = out + (size_t)b * SEG;
    for (int i = threadIdx.x; i < SEG; i += THREADS) {
        unsigned c = hist[i];
        if (c) atomicAdd(&gout[i], c);
    }
}

__global__ void finalize_kernel(const unsigned* cnt, float* out,
                                const float* __restrict__ w, int n) {
    int i = blockIdx.x * blockDim.x + threadIdx.x;
    if (i < n) {
        unsigned c = cnt[i];
        out[i] = (float)c * w[i & (SEG - 1)];
    }
}

extern "C" void kernel_launch(void* const* d_in, const int* in_sizes, int n_in,
                              void* d_out, int out_size, void* d_ws, size_t ws_size,
                              hipStream_t stream) {
    const float* x = (const float*)d_in[0];
    const float* w = (const float*)d_in[1];
    float* out = (float*)d_out;

    const size_t ws_needed = (size_t)B_DIM * CHUNKS * SEG * sizeof(unsigned); // 16 MiB

    if (ws_size >= ws_needed && d_ws != nullptr) {
        unsigned* part = (unsigned*)d_ws;
        dim3 grid(CHUNKS, B_DIM);
        hist_part<<<grid, THREADS, 0, stream>>>(x, part);
        int nt = B_DIM * (SEG / 4);                    // 65536 threads
        reduce_fin<<<(nt + 255) / 256, 256, 0, stream>>>(part, out, w);
    } else {
        // Fallback: old path with global atomic merge.
        hipMemsetAsync(d_out, 0, (size_t)out_size * sizeof(float), stream);
        dim3 grid(CHUNKS, B_DIM);
        hist_kernel<<<grid, THREADS, 0, stream>>>(x, (unsigned*)d_out);
        int n = out_size;
        finalize_kernel<<<(n + 255) / 256, 256, 0, stream>>>((const unsigned*)d_out, out, w, n);
    }
}